// Round 2
// baseline (3597.938 us; speedup 1.0000x reference)
//
#include <hip/hip_runtime.h>

typedef __attribute__((ext_vector_type(8))) short short8;
typedef __attribute__((ext_vector_type(4))) float floatx4;
typedef unsigned long long u64;
typedef unsigned short ushort;

#define DEV __device__ __forceinline__

constexpr int B_ = 128, T_ = 256, D_ = 512, L_ = 1024;

// ---- workspace byte offsets (layout unchanged) ----
constexpr size_t OFF_PREZ = 0;                                  // fp16 [T][B][L]
constexpr size_t OFF_PRER = OFF_PREZ + (size_t)T_ * B_ * L_ * 2;
constexpr size_t OFF_WH   = OFF_PRER + (size_t)T_ * B_ * L_ * 2; // bf16 [3][1024][1024]
constexpr size_t OFF_WX   = OFF_WH + (size_t)3 * L_ * 1024 * 2;  // bf16 [3][1024][512]
constexpr size_t OFF_XB   = OFF_WX + (size_t)3 * L_ * 512 * 2;   // bf16 [B][T][D]
constexpr size_t OFF_HB   = OFF_XB + (size_t)B_ * T_ * D_ * 2;   // bf16 [B][L] current h
constexpr size_t OFF_RH   = OFF_HB + (size_t)B_ * L_ * 2;        // bf16 [B][L] r*h
constexpr size_t OFF_Z    = OFF_RH + (size_t)B_ * L_ * 2;        // (unused)
constexpr size_t OFF_CTR  = OFF_Z + (size_t)B_ * L_ * 4;         // barrier flags (16 KB)

DEV ushort f2bf(float f) {
  unsigned u = __float_as_uint(f);
  u += 0x7fffu + ((u >> 16) & 1u);   // RNE
  return (ushort)(u >> 16);
}
DEV ushort f2h(float f) { _Float16 h = (_Float16)f; return __builtin_bit_cast(ushort, h); }
DEV float h2f(ushort u) { _Float16 h = __builtin_bit_cast(_Float16, u); return (float)h; }
DEV float sigmoidf_(float x) { return 1.0f / (1.0f + __expf(-x)); }
DEV float tanhf_(float x) {
  float a = fabsf(x);
  float e = __expf(-2.0f * a);
  float t = (1.0f - e) / (1.0f + e);
  return copysignf(t, x);
}

// ---- agent-scope (MALL-coherent) access helpers — verified primitives from R0 ----
DEV u64 cload64(const void* p) {
  return __hip_atomic_load((const u64*)p, __ATOMIC_RELAXED, __HIP_MEMORY_SCOPE_AGENT);
}
DEV void cstore64(void* p, u64 v) {
  __hip_atomic_store((u64*)p, v, __ATOMIC_RELAXED, __HIP_MEMORY_SCOPE_AGENT);
}
DEV u64 pack2f(float a, float b) { float2 t; t.x = a; t.y = b; return __builtin_bit_cast(u64, t); }

DEV void gld_lds16(const void* g, void* l) {
  __builtin_amdgcn_global_load_lds(
      (const __attribute__((address_space(1))) unsigned int*)g,
      (__attribute__((address_space(3))) unsigned int*)l, 16, 0, 0);
}

// early-issue prefetches (plain cached loads, pinned at issue point)
DEV u64 prefetch8(const ushort* p) {
  u64 v; asm volatile("global_load_dwordx2 %0, %1, off" : "=v"(v) : "v"(p)); return v;
}
DEV floatx4 prefetch16f(const float* p) {
  floatx4 v; asm volatile("global_load_dwordx4 %0, %1, off" : "=v"(v) : "v"(p)); return v;
}

// ---- flat grid barrier: 256 flags, parity-alternated arrays, equality poll ----
// sig: every wave drains its stores, block syncs, then tid0 publishes flag.
// wait: wave 0 polls 4 flags/lane (2 u64 agent loads) until all == iv.
DEV void gbar_sig(unsigned* flags, int p, unsigned iv) {
  asm volatile("s_waitcnt vmcnt(0)" ::: "memory");
  __syncthreads();
  if (threadIdx.x == 0)
    __hip_atomic_store(flags + ((iv & 1) << 8) + p, iv, __ATOMIC_RELAXED, __HIP_MEMORY_SCOPE_AGENT);
}
DEV void gbar_wait(const unsigned* flags, unsigned iv) {
  const unsigned* f = flags + ((iv & 1) << 8);
  if (threadIdx.x < 64) {
    const u64* q = (const u64*)(f + (threadIdx.x << 2));
    for (;;) {
      u64 a = cload64(q);
      u64 b = cload64(q + 1);
      bool bad = ((unsigned)a != iv) | ((unsigned)(a >> 32) != iv) |
                 ((unsigned)b != iv) | ((unsigned)(b >> 32) != iv);
      if (!__ballot(bad)) break;
    }
  }
  __syncthreads();
}

// ---------------- conversion kernels (unchanged, verified) ----------------
__global__ __launch_bounds__(256) void k_conv_x(const float* __restrict__ x,
                                                unsigned short* __restrict__ xb) {
  size_t i = ((size_t)blockIdx.x * 256 + threadIdx.x) * 8;
  float4 f0 = *(const float4*)(x + i);
  float4 f1 = *(const float4*)(x + i + 4);
  short8 o;
  o[0] = (short)f2bf(f0.x); o[1] = (short)f2bf(f0.y); o[2] = (short)f2bf(f0.z); o[3] = (short)f2bf(f0.w);
  o[4] = (short)f2bf(f1.x); o[5] = (short)f2bf(f1.y); o[6] = (short)f2bf(f1.z); o[7] = (short)f2bf(f1.w);
  *(short8*)&xb[i] = o;
}

__global__ __launch_bounds__(256) void k_conv_w(const float* __restrict__ Wz,
                                                const float* __restrict__ Wr,
                                                const float* __restrict__ Wi,
                                                unsigned short* __restrict__ wx,
                                                unsigned short* __restrict__ wh) {
  int idx = blockIdx.x * 256 + threadIdx.x;
  int g = idx / 196608;
  int rem = idx - g * 196608;
  int n = rem / 192;
  int c = rem - n * 192;
  int k = c * 8;
  const float* W = (g == 0) ? Wz : ((g == 1) ? Wr : Wi);
  const float* src = W + (size_t)n * 1536 + k;
  short8 o;
#pragma unroll
  for (int u = 0; u < 8; ++u) o[u] = (short)f2bf(src[u]);
  if (k < 512)
    *(short8*)&wx[((size_t)g * 1024 + n) * 512 + k] = o;
  else
    *(short8*)&wh[((size_t)g * 1024 + n) * 1024 + (k - 512)] = o;
}

// ---------------- x-part pre-activation GEMM (unchanged, verified) ----------------
__global__ __launch_bounds__(256) void k_pre_gemm(const unsigned short* __restrict__ xb,
                                                  const unsigned short* __restrict__ wx,
                                                  unsigned short* __restrict__ preZ,
                                                  unsigned short* __restrict__ preR,
                                                  float* __restrict__ outI,
                                                  const float* __restrict__ bz,
                                                  const float* __restrict__ br,
                                                  const float* __restrict__ bi) {
  __shared__ __align__(16) unsigned short As[128 * 64];
  __shared__ __align__(16) unsigned short Bs[128 * 64];
  const int tid = threadIdx.x;
  const int wave = tid >> 6, lane = tid & 63;
  const int m0 = blockIdx.x * 128;
  const int n0g = blockIdx.y * 128;
  const int g = n0g >> 10;
  const int n0 = n0g & 1023;
  const unsigned short* wg = wx + (size_t)g * 1024 * 512;
  const int wm = (wave >> 1) * 64, wn = (wave & 1) * 64;

  floatx4 acc[4][4];
#pragma unroll
  for (int i = 0; i < 4; ++i)
#pragma unroll
    for (int j = 0; j < 4; ++j) acc[i][j] = (floatx4){0.f, 0.f, 0.f, 0.f};

  for (int ko = 0; ko < 8; ++ko) {
    const int k0 = ko * 64;
#pragma unroll
    for (int j = 0; j < 4; ++j) {
      int rowbase = (wave * 4 + j) * 8;
      int row = rowbase + (lane >> 3);
      int clog = (lane & 7) ^ (row & 7);
      gld_lds16(xb + (size_t)(m0 + row) * 512 + k0 + clog * 8, &As[rowbase * 64]);
      gld_lds16(wg + (size_t)(n0 + row) * 512 + k0 + clog * 8, &Bs[rowbase * 64]);
    }
    __syncthreads();
#pragma unroll
    for (int ks = 0; ks < 2; ++ks) {
      short8 a[4], b[4];
      int cl = ks * 4 + (lane >> 4);
#pragma unroll
      for (int i = 0; i < 4; ++i) {
        int r = wm + i * 16 + (lane & 15);
        a[i] = *(const short8*)&As[r * 64 + ((cl ^ (r & 7)) * 8)];
      }
#pragma unroll
      for (int j = 0; j < 4; ++j) {
        int r = wn + j * 16 + (lane & 15);
        b[j] = *(const short8*)&Bs[r * 64 + ((cl ^ (r & 7)) * 8)];
      }
#pragma unroll
      for (int i = 0; i < 4; ++i)
#pragma unroll
        for (int j = 0; j < 4; ++j)
          acc[i][j] = __builtin_amdgcn_mfma_f32_16x16x32_bf16(a[i], b[j], acc[i][j], 0, 0, 0);
    }
    __syncthreads();
  }

  const float* bias = (g == 0) ? bz : ((g == 1) ? br : bi);
#pragma unroll
  for (int i = 0; i < 4; ++i)
#pragma unroll
    for (int j = 0; j < 4; ++j) {
      int ncol = n0 + wn + j * 16 + (lane & 15);
      float bv = bias[ncol];
#pragma unroll
      for (int reg = 0; reg < 4; ++reg) {
        int m = m0 + wm + i * 16 + (lane >> 4) * 4 + reg;
        int bidx = m >> 8, t = m & 255;
        size_t idx = ((size_t)(t * B_ + bidx) << 10) + ncol;
        float v = acc[i][j][reg] + bv;
        if (g == 0)      preZ[idx] = f2h(v);
        else if (g == 1) preR[idx] = f2h(v);
        else             outI[idx] = v;                // pre_i parked in d_out
      }
    }
}

// =====================================================================
// Persistent recurrent kernel — placement-independent (agent-scope MALL
// exchange, correct under ANY workgroup->XCD mapping; Guideline 16).
// 256 blocks, 1/CU. Block p: batch rows [16*(p>>5), +16), latent cols
// [32*(p&31), +32) for z, r AND i  ->  z and h_prev stay in registers/LDS;
// only h-slab and rh-slab cross blocks (16 rows x 1024 bf16 each).
// Barriers: flat 256-flag parity arrays + wave-parallel equality poll.
// =====================================================================
__global__ __launch_bounds__(256, 1) void k_gru(const unsigned short* __restrict__ wh,
                                                const unsigned short* __restrict__ preZ,
                                                const unsigned short* __restrict__ preR,
                                                unsigned short* __restrict__ hb,
                                                unsigned short* __restrict__ rh,
                                                float* __restrict__ out,
                                                unsigned* __restrict__ flags) {
  __shared__ __align__(16) unsigned short WA[64 * 1024];  // 128 KB: rows 0-31 Wz-cols, 32-63 Wr-cols
  __shared__ __align__(16) unsigned short Hs[16 * 512];   // 16 KB staging (K-half of 16-row slab)
  __shared__ __align__(16) float red[512];                //  2 KB phase-B cross-wave reduce
  __shared__ __align__(16) float hstash[512];             //  2 KB h_{t-1} f32 [16 m][32 local n]

  const int tid = threadIdx.x, wave = tid >> 6, lane = tid & 63;
  const int p = blockIdx.x;
  const int r0 = (p >> 5) * 16;          // batch rows r0..r0+16
  const int c0 = (p & 31) * 32;          // latent cols c0..c0+32 (z, r and i)

  const unsigned short* wzp = wh + (size_t)c0 * 1024;
  const unsigned short* wrp = wh + (size_t)1048576 + (size_t)c0 * 1024;
  const unsigned short* wip = wh + (size_t)2097152 + (size_t)c0 * 1024;

  // one-time LDS residency of Wz/Wr tiles (swizzled, 16B-chunk xor)
  for (int idx = tid; idx < 64 * 128; idx += 256) {
    int row = idx >> 7, cl = idx & 127;
    const unsigned short* src = (row < 32) ? (wzp + (size_t)row * 1024 + cl * 8)
                                           : (wrp + (size_t)(row - 32) * 1024 + cl * 8);
    *(short8*)&WA[row * 1024 + ((cl ^ (row & 7))) * 8] = *(const short8*)src;
  }
  hstash[tid] = 0.f;
  hstash[tid + 256] = 0.f;
  __syncthreads();

  // fixed per-thread coordinates
  const int mrow = lane & 15;                               // batch row within slab
  const int nloc = ((wave & 1) << 4) + ((lane >> 4) << 2);  // 4 consecutive local cols
  const int arow = wave * 16 + mrow;                        // WA row (phase A)
  const int ax = arow & 7, hx = mrow & 7;
  const unsigned short* preX = (wave < 2) ? preZ : preR;
  const size_t prebase = ((size_t)(r0 + mrow) << 10) + (size_t)(c0 + nloc);
  const unsigned short* hbs = hb + (size_t)r0 * 1024;
  const unsigned short* rhs = rh + (size_t)r0 * 1024;
  // staging coords: 16 threads/row, u64 granules
  const int srow = tid >> 4, scol = tid & 15, sx2 = srow & 7;

  u64 preX8 = *(const u64*)(preX + prebase);                // t=0 pre-activation
  unsigned bseq = 0;
  float zreg[4] = {0.f, 0.f, 0.f, 0.f};
  float hprev[4] = {0.f, 0.f, 0.f, 0.f};

  for (int t = 0; t < T_; ++t) {
    // =================== PHASE A: z|r = sigmoid(Wh·h + pre) ===================
    u64 v[16];
    {
      const unsigned short* src = hbs + (size_t)srow * 1024;
#pragma unroll
      for (int j = 0; j < 8; ++j) v[j]     = cload64(src + (size_t)(scol + j * 16) * 4);
#pragma unroll
      for (int j = 0; j < 8; ++j) v[8 + j] = cload64(src + 512 + (size_t)(scol + j * 16) * 4);
    }
#pragma unroll
    for (int j = 0; j < 8; ++j) {                            // commit half0 (waits vmcnt(8))
      int u = scol + j * 16;
      *(u64*)&Hs[srow * 512 + (((u >> 1) ^ sx2)) * 8 + (u & 1) * 4] = v[j];
    }
    __syncthreads();

    floatx4 acc0 = (floatx4){0.f, 0.f, 0.f, 0.f};
    floatx4 acc1 = (floatx4){0.f, 0.f, 0.f, 0.f};
#pragma unroll
    for (int ks = 0; ks < 16; ks += 2) {
      const int ck0 = ks * 4 + (lane >> 4), ck1 = ck0 + 4;
      short8 w0 = *(const short8*)&WA[arow * 1024 + ((ck0 ^ ax)) * 8];
      short8 h0 = *(const short8*)&Hs[mrow * 512 + ((ck0 ^ hx)) * 8];
      acc0 = __builtin_amdgcn_mfma_f32_16x16x32_bf16(w0, h0, acc0, 0, 0, 0);
      short8 w1 = *(const short8*)&WA[arow * 1024 + ((ck1 ^ ax)) * 8];
      short8 h1 = *(const short8*)&Hs[mrow * 512 + ((ck1 ^ hx)) * 8];
      acc1 = __builtin_amdgcn_mfma_f32_16x16x32_bf16(w1, h1, acc1, 0, 0, 0);
    }
    __syncthreads();
#pragma unroll
    for (int j = 0; j < 8; ++j) {                            // commit half1
      int u = scol + j * 16;
      *(u64*)&Hs[srow * 512 + (((u >> 1) ^ sx2)) * 8 + (u & 1) * 4] = v[8 + j];
    }
    __syncthreads();
#pragma unroll
    for (int ks = 0; ks < 16; ks += 2) {
      const int ck0 = ks * 4 + (lane >> 4), ck1 = ck0 + 4;
      short8 w0 = *(const short8*)&WA[arow * 1024 + (((64 + ck0) ^ ax)) * 8];
      short8 h0 = *(const short8*)&Hs[mrow * 512 + ((ck0 ^ hx)) * 8];
      acc0 = __builtin_amdgcn_mfma_f32_16x16x32_bf16(w0, h0, acc0, 0, 0, 0);
      short8 w1 = *(const short8*)&WA[arow * 1024 + (((64 + ck1) ^ ax)) * 8];
      short8 h1 = *(const short8*)&Hs[mrow * 512 + ((ck1 ^ hx)) * 8];
      acc1 = __builtin_amdgcn_mfma_f32_16x16x32_bf16(w1, h1, acc1, 0, 0, 0);
    }

    // epilogue A: C mapping row=(lane>>4)*4+reg -> n (W first operand), col=lane&15 -> m
    {
      floatx4 accA = acc0 + acc1;
      if (wave < 2) {
#pragma unroll
        for (int r2 = 0; r2 < 4; ++r2)
          zreg[r2] = sigmoidf_(accA[r2] + h2f((ushort)(preX8 >> (16 * r2))));
      } else {
        const floatx4 hp = *(const floatx4*)&hstash[mrow * 32 + nloc];
        u64 o = 0;
#pragma unroll
        for (int r2 = 0; r2 < 4; ++r2) {
          float rg = sigmoidf_(accA[r2] + h2f((ushort)(preX8 >> (16 * r2))));
          o |= (u64)f2bf(rg * hp[r2]) << (16 * r2);
        }
        cstore64(rh + (size_t)(r0 + mrow) * 1024 + c0 + nloc, o);
      }
    }
    ++bseq;
    gbar_sig(flags, p, bseq);
    floatx4 preI4 = prefetch16f(out + ((size_t)t << 17) + prebase);  // parked pre_i
    gbar_wait(flags, bseq);

    // =================== PHASE B: i = tanh(Wi·(r*h) + pre_i); h update ===================
    {
      const unsigned short* src = rhs + (size_t)srow * 1024;
#pragma unroll
      for (int j = 0; j < 8; ++j) v[j]     = cload64(src + (size_t)(scol + j * 16) * 4);
#pragma unroll
      for (int j = 0; j < 8; ++j) v[8 + j] = cload64(src + 512 + (size_t)(scol + j * 16) * 4);
    }
#pragma unroll
    for (int j = 0; j < 8; ++j) {
      int u = scol + j * 16;
      *(u64*)&Hs[srow * 512 + (((u >> 1) ^ sx2)) * 8 + (u & 1) * 4] = v[j];
    }
    __syncthreads();

    floatx4 accB0 = (floatx4){0.f, 0.f, 0.f, 0.f};
    floatx4 accB1 = (floatx4){0.f, 0.f, 0.f, 0.f};
    const unsigned short* wb = wip + (size_t)(((wave & 1) << 4) + mrow) * 1024 + ((size_t)(wave >> 1) << 9);
    if ((wave >> 1) == 0) {
#pragma unroll
      for (int ks = 0; ks < 16; ks += 2) {
        const int ck0 = ks * 4 + (lane >> 4), ck1 = ck0 + 4;
        short8 w0 = *(const short8*)(wb + ck0 * 8);
        short8 b0 = *(const short8*)&Hs[mrow * 512 + ((ck0 ^ hx)) * 8];
        accB0 = __builtin_amdgcn_mfma_f32_16x16x32_bf16(w0, b0, accB0, 0, 0, 0);
        short8 w1 = *(const short8*)(wb + ck1 * 8);
        short8 b1 = *(const short8*)&Hs[mrow * 512 + ((ck1 ^ hx)) * 8];
        accB1 = __builtin_amdgcn_mfma_f32_16x16x32_bf16(w1, b1, accB1, 0, 0, 0);
      }
    }
    __syncthreads();
#pragma unroll
    for (int j = 0; j < 8; ++j) {
      int u = scol + j * 16;
      *(u64*)&Hs[srow * 512 + (((u >> 1) ^ sx2)) * 8 + (u & 1) * 4] = v[8 + j];
    }
    __syncthreads();
    if ((wave >> 1) == 1) {
#pragma unroll
      for (int ks = 0; ks < 16; ks += 2) {
        const int ck0 = ks * 4 + (lane >> 4), ck1 = ck0 + 4;
        short8 w0 = *(const short8*)(wb + ck0 * 8);
        short8 b0 = *(const short8*)&Hs[mrow * 512 + ((ck0 ^ hx)) * 8];
        accB0 = __builtin_amdgcn_mfma_f32_16x16x32_bf16(w0, b0, accB0, 0, 0, 0);
        short8 w1 = *(const short8*)(wb + ck1 * 8);
        short8 b1 = *(const short8*)&Hs[mrow * 512 + ((ck1 ^ hx)) * 8];
        accB1 = __builtin_amdgcn_mfma_f32_16x16x32_bf16(w1, b1, accB1, 0, 0, 0);
      }
      floatx4 sB = accB0 + accB1;
      *(floatx4*)&red[((wave - 2) << 8) + (lane << 2)] = sB;
    }
    __syncthreads();
    if (wave < 2) {
      floatx4 accB = accB0 + accB1 + *(const floatx4*)&red[(wave << 8) + (lane << 2)];
      float hn[4];
      u64 ob = 0;
#pragma unroll
      for (int r2 = 0; r2 < 4; ++r2) {
        float ivl = tanhf_(accB[r2] + preI4[r2]);
        hn[r2] = (1.f - zreg[r2]) * hprev[r2] + zreg[r2] * ivl;
        hprev[r2] = hn[r2];
        ob |= (u64)f2bf(hn[r2]) << (16 * r2);
      }
      float* po = out + ((size_t)t << 17) + prebase;
      *(floatx4*)po = (floatx4){hn[0], hn[1], hn[2], hn[3]};
      cstore64(hb + (size_t)(r0 + mrow) * 1024 + c0 + nloc, ob);
      *(floatx4*)&hstash[mrow * 32 + nloc] = (floatx4){hn[0], hn[1], hn[2], hn[3]};
    }

    if (t + 1 < T_) {
      ++bseq;
      gbar_sig(flags, p, bseq);
      preX8 = prefetch8(preX + ((size_t)(t + 1) << 17) + prebase);
      gbar_wait(flags, bseq);
    }
  }
}

extern "C" void kernel_launch(void* const* d_in, const int* in_sizes, int n_in,
                              void* d_out, int out_size, void* d_ws, size_t ws_size,
                              hipStream_t stream) {
  const float* x  = (const float*)d_in[0];
  const float* Wz = (const float*)d_in[1];
  const float* bz = (const float*)d_in[2];
  const float* Wr = (const float*)d_in[3];
  const float* br = (const float*)d_in[4];
  const float* Wi = (const float*)d_in[5];
  const float* bi = (const float*)d_in[6];
  float* out = (float*)d_out;
  char* wsb = (char*)d_ws;

  unsigned short* preZ = (unsigned short*)(wsb + OFF_PREZ);
  unsigned short* preR = (unsigned short*)(wsb + OFF_PRER);
  unsigned short* wh   = (unsigned short*)(wsb + OFF_WH);
  unsigned short* wx   = (unsigned short*)(wsb + OFF_WX);
  unsigned short* xb   = (unsigned short*)(wsb + OFF_XB);
  unsigned short* hb   = (unsigned short*)(wsb + OFF_HB);
  unsigned short* rh   = (unsigned short*)(wsb + OFF_RH);
  unsigned* flags      = (unsigned*)(wsb + OFF_CTR);

  hipMemsetAsync(wsb + OFF_HB, 0, (size_t)B_ * L_ * 2, stream);   // h0 = 0
  hipMemsetAsync(wsb + OFF_CTR, 0, 16384, stream);                // barrier flags

  k_conv_x<<<8192, 256, 0, stream>>>(x, xb);
  k_conv_w<<<2304, 256, 0, stream>>>(Wz, Wr, Wi, wx, wh);
  k_pre_gemm<<<dim3(256, 24), 256, 0, stream>>>(xb, wx, preZ, preR, out, bz, br, bi);
  k_gru<<<256, 256, 0, stream>>>(wh, preZ, preR, hb, rh, out, flags);
}

// Round 3
// 2486.815 us; speedup vs baseline: 1.4468x; 1.4468x over previous
//
#include <hip/hip_runtime.h>

typedef __attribute__((ext_vector_type(8))) short short8;
typedef __attribute__((ext_vector_type(4))) float floatx4;
typedef unsigned long long u64;
typedef unsigned short ushort;

#define DEV __device__ __forceinline__

constexpr int B_ = 128, T_ = 256, D_ = 512, L_ = 1024;

// ---- workspace byte offsets (layout unchanged) ----
constexpr size_t OFF_PREZ = 0;                                  // fp16 [T][B][L]
constexpr size_t OFF_PRER = OFF_PREZ + (size_t)T_ * B_ * L_ * 2;
constexpr size_t OFF_WH   = OFF_PRER + (size_t)T_ * B_ * L_ * 2; // bf16 [3][1024][1024]
constexpr size_t OFF_WX   = OFF_WH + (size_t)3 * L_ * 1024 * 2;  // bf16 [3][1024][512]
constexpr size_t OFF_XB   = OFF_WX + (size_t)3 * L_ * 512 * 2;   // bf16 [B][T][D]
constexpr size_t OFF_HB   = OFF_XB + (size_t)B_ * T_ * D_ * 2;   // bf16 [B][L] current h
constexpr size_t OFF_RH   = OFF_HB + (size_t)B_ * L_ * 2;        // bf16 [B][L] r*h
constexpr size_t OFF_Z    = OFF_RH + (size_t)B_ * L_ * 2;        // (unused)
constexpr size_t OFF_CTR  = OFF_Z + (size_t)B_ * L_ * 4;         // barrier flags (16 KB)

DEV ushort f2bf(float f) {
  unsigned u = __float_as_uint(f);
  u += 0x7fffu + ((u >> 16) & 1u);   // RNE
  return (ushort)(u >> 16);
}
DEV ushort f2h(float f) { _Float16 h = (_Float16)f; return __builtin_bit_cast(ushort, h); }
DEV float h2f(ushort u) { _Float16 h = __builtin_bit_cast(_Float16, u); return (float)h; }
DEV float sigmoidf_(float x) { return 1.0f / (1.0f + __expf(-x)); }
DEV float tanhf_(float x) {
  float a = fabsf(x);
  float e = __expf(-2.0f * a);
  float t = (1.0f - e) / (1.0f + e);
  return copysignf(t, x);
}

// ---- agent-scope (MALL-coherent) access helpers — verified primitives ----
DEV u64 cload64(const void* p) {
  return __hip_atomic_load((const u64*)p, __ATOMIC_RELAXED, __HIP_MEMORY_SCOPE_AGENT);
}
DEV void cstore64(void* p, u64 v) {
  __hip_atomic_store((u64*)p, v, __ATOMIC_RELAXED, __HIP_MEMORY_SCOPE_AGENT);
}

DEV void gld_lds16(const void* g, void* l) {
  __builtin_amdgcn_global_load_lds(
      (const __attribute__((address_space(1))) unsigned int*)g,
      (__attribute__((address_space(3))) unsigned int*)l, 16, 0, 0);
}

// early-issue prefetches (plain cached loads, pinned at issue point)
DEV u64 prefetch8(const ushort* p) {
  u64 v; asm volatile("global_load_dwordx2 %0, %1, off" : "=v"(v) : "v"(p)); return v;
}
DEV floatx4 prefetch16f(const float* p) {
  floatx4 v; asm volatile("global_load_dwordx4 %0, %1, off" : "=v"(v) : "v"(p)); return v;
}

// ---- slab-local barrier: 32 blocks of one batch-row group sync together ----
// flags layout: [(parity*8 + rg)*32 + slot], one 128B line per group+parity.
// sig: drain stores (vmcnt), block-sync, tid0 publishes flag = iv.
// wait: lanes poll 1 flag each (coalesced 128B MALL read), s_sleep backoff.
// Equality compare + parity arrays -> no reset needed, graph-replay safe
// (flags memset each launch). Overwrite-safety: a block can only reach
// sig(iv+2) (same parity as iv) after wait(iv+1) completed, which requires
// every slab block to have passed wait(iv) -> nobody still polls iv.
DEV void gbar_sig(unsigned* flags, int rg, int slot, unsigned iv) {
  asm volatile("s_waitcnt vmcnt(0)" ::: "memory");
  __syncthreads();
  if (threadIdx.x == 0)
    __hip_atomic_store(flags + (((iv & 1) << 3) + rg) * 32 + slot, iv,
                       __ATOMIC_RELAXED, __HIP_MEMORY_SCOPE_AGENT);
}
DEV void gbar_wait(const unsigned* flags, int rg, unsigned iv) {
  if (threadIdx.x < 64) {
    const unsigned* f = flags + (((iv & 1) << 3) + rg) * 32 + (threadIdx.x & 31);
    while (__ballot(__hip_atomic_load(f, __ATOMIC_RELAXED, __HIP_MEMORY_SCOPE_AGENT) != iv))
      __builtin_amdgcn_s_sleep(1);
  }
  __syncthreads();
}

// ---------------- conversion kernels (unchanged, verified) ----------------
__global__ __launch_bounds__(256) void k_conv_x(const float* __restrict__ x,
                                                unsigned short* __restrict__ xb) {
  size_t i = ((size_t)blockIdx.x * 256 + threadIdx.x) * 8;
  float4 f0 = *(const float4*)(x + i);
  float4 f1 = *(const float4*)(x + i + 4);
  short8 o;
  o[0] = (short)f2bf(f0.x); o[1] = (short)f2bf(f0.y); o[2] = (short)f2bf(f0.z); o[3] = (short)f2bf(f0.w);
  o[4] = (short)f2bf(f1.x); o[5] = (short)f2bf(f1.y); o[6] = (short)f2bf(f1.z); o[7] = (short)f2bf(f1.w);
  *(short8*)&xb[i] = o;
}

__global__ __launch_bounds__(256) void k_conv_w(const float* __restrict__ Wz,
                                                const float* __restrict__ Wr,
                                                const float* __restrict__ Wi,
                                                unsigned short* __restrict__ wx,
                                                unsigned short* __restrict__ wh) {
  int idx = blockIdx.x * 256 + threadIdx.x;
  int g = idx / 196608;
  int rem = idx - g * 196608;
  int n = rem / 192;
  int c = rem - n * 192;
  int k = c * 8;
  const float* W = (g == 0) ? Wz : ((g == 1) ? Wr : Wi);
  const float* src = W + (size_t)n * 1536 + k;
  short8 o;
#pragma unroll
  for (int u = 0; u < 8; ++u) o[u] = (short)f2bf(src[u]);
  if (k < 512)
    *(short8*)&wx[((size_t)g * 1024 + n) * 512 + k] = o;
  else
    *(short8*)&wh[((size_t)g * 1024 + n) * 1024 + (k - 512)] = o;
}

// ---------------- x-part pre-activation GEMM (unchanged, verified) ----------------
__global__ __launch_bounds__(256) void k_pre_gemm(const unsigned short* __restrict__ xb,
                                                  const unsigned short* __restrict__ wx,
                                                  unsigned short* __restrict__ preZ,
                                                  unsigned short* __restrict__ preR,
                                                  float* __restrict__ outI,
                                                  const float* __restrict__ bz,
                                                  const float* __restrict__ br,
                                                  const float* __restrict__ bi) {
  __shared__ __align__(16) unsigned short As[128 * 64];
  __shared__ __align__(16) unsigned short Bs[128 * 64];
  const int tid = threadIdx.x;
  const int wave = tid >> 6, lane = tid & 63;
  const int m0 = blockIdx.x * 128;
  const int n0g = blockIdx.y * 128;
  const int g = n0g >> 10;
  const int n0 = n0g & 1023;
  const unsigned short* wg = wx + (size_t)g * 1024 * 512;
  const int wm = (wave >> 1) * 64, wn = (wave & 1) * 64;

  floatx4 acc[4][4];
#pragma unroll
  for (int i = 0; i < 4; ++i)
#pragma unroll
    for (int j = 0; j < 4; ++j) acc[i][j] = (floatx4){0.f, 0.f, 0.f, 0.f};

  for (int ko = 0; ko < 8; ++ko) {
    const int k0 = ko * 64;
#pragma unroll
    for (int j = 0; j < 4; ++j) {
      int rowbase = (wave * 4 + j) * 8;
      int row = rowbase + (lane >> 3);
      int clog = (lane & 7) ^ (row & 7);
      gld_lds16(xb + (size_t)(m0 + row) * 512 + k0 + clog * 8, &As[rowbase * 64]);
      gld_lds16(wg + (size_t)(n0 + row) * 512 + k0 + clog * 8, &Bs[rowbase * 64]);
    }
    __syncthreads();
#pragma unroll
    for (int ks = 0; ks < 2; ++ks) {
      short8 a[4], b[4];
      int cl = ks * 4 + (lane >> 4);
#pragma unroll
      for (int i = 0; i < 4; ++i) {
        int r = wm + i * 16 + (lane & 15);
        a[i] = *(const short8*)&As[r * 64 + ((cl ^ (r & 7)) * 8)];
      }
#pragma unroll
      for (int j = 0; j < 4; ++j) {
        int r = wn + j * 16 + (lane & 15);
        b[j] = *(const short8*)&Bs[r * 64 + ((cl ^ (r & 7)) * 8)];
      }
#pragma unroll
      for (int i = 0; i < 4; ++i)
#pragma unroll
        for (int j = 0; j < 4; ++j)
          acc[i][j] = __builtin_amdgcn_mfma_f32_16x16x32_bf16(a[i], b[j], acc[i][j], 0, 0, 0);
    }
    __syncthreads();
  }

  const float* bias = (g == 0) ? bz : ((g == 1) ? br : bi);
#pragma unroll
  for (int i = 0; i < 4; ++i)
#pragma unroll
    for (int j = 0; j < 4; ++j) {
      int ncol = n0 + wn + j * 16 + (lane & 15);
      float bv = bias[ncol];
#pragma unroll
      for (int reg = 0; reg < 4; ++reg) {
        int m = m0 + wm + i * 16 + (lane >> 4) * 4 + reg;
        int bidx = m >> 8, t = m & 255;
        size_t idx = ((size_t)(t * B_ + bidx) << 10) + ncol;
        float v = acc[i][j][reg] + bv;
        if (g == 0)      preZ[idx] = f2h(v);
        else if (g == 1) preR[idx] = f2h(v);
        else             outI[idx] = v;                // pre_i parked in d_out
      }
    }
}

// =====================================================================
// Persistent recurrent kernel — placement-independent (agent-scope MALL
// exchange; correct under ANY workgroup->XCD mapping). 256 blocks, 1/CU.
// Block p: batch rows [16*(p>>5), +16), latent cols [32*(p&31), +32) for
// z, r AND i -> z and h_prev stay in registers/LDS; only h-slab and
// rh-slab cross blocks. Barriers are SLAB-LOCAL (32 blocks of a row
// group), flag-based, s_sleep backoff — slabs drift independently.
// =====================================================================
__global__ __launch_bounds__(256, 1) void k_gru(const unsigned short* __restrict__ wh,
                                                const unsigned short* __restrict__ preZ,
                                                const unsigned short* __restrict__ preR,
                                                unsigned short* __restrict__ hb,
                                                unsigned short* __restrict__ rh,
                                                float* __restrict__ out,
                                                unsigned* __restrict__ flags) {
  __shared__ __align__(16) unsigned short WA[64 * 1024];  // 128 KB: rows 0-31 Wz-cols, 32-63 Wr-cols
  __shared__ __align__(16) unsigned short Hs[16 * 512];   // 16 KB staging (K-half of 16-row slab)
  __shared__ __align__(16) float red[512];                //  2 KB phase-B cross-wave reduce
  __shared__ __align__(16) float hstash[512];             //  2 KB h_{t-1} f32 [16 m][32 local n]

  const int tid = threadIdx.x, wave = tid >> 6, lane = tid & 63;
  const int p = blockIdx.x;
  const int rg = p >> 5;                 // row group (slab) id, 0..7
  const int slot = p & 31;               // column-group slot within slab
  const int r0 = rg * 16;                // batch rows r0..r0+16
  const int c0 = slot * 32;              // latent cols c0..c0+32 (z, r and i)

  const unsigned short* wzp = wh + (size_t)c0 * 1024;
  const unsigned short* wrp = wh + (size_t)1048576 + (size_t)c0 * 1024;
  const unsigned short* wip = wh + (size_t)2097152 + (size_t)c0 * 1024;

  // one-time LDS residency of Wz/Wr tiles (swizzled, 16B-chunk xor)
  for (int idx = tid; idx < 64 * 128; idx += 256) {
    int row = idx >> 7, cl = idx & 127;
    const unsigned short* src = (row < 32) ? (wzp + (size_t)row * 1024 + cl * 8)
                                           : (wrp + (size_t)(row - 32) * 1024 + cl * 8);
    *(short8*)&WA[row * 1024 + ((cl ^ (row & 7))) * 8] = *(const short8*)src;
  }
  hstash[tid] = 0.f;
  hstash[tid + 256] = 0.f;
  __syncthreads();

  // fixed per-thread coordinates
  const int mrow = lane & 15;                               // batch row within slab
  const int nloc = ((wave & 1) << 4) + ((lane >> 4) << 2);  // 4 consecutive local cols
  const int arow = wave * 16 + mrow;                        // WA row (phase A)
  const int ax = arow & 7, hx = mrow & 7;
  const unsigned short* preX = (wave < 2) ? preZ : preR;
  const size_t prebase = ((size_t)(r0 + mrow) << 10) + (size_t)(c0 + nloc);
  const unsigned short* hbs = hb + (size_t)r0 * 1024;
  const unsigned short* rhs = rh + (size_t)r0 * 1024;
  // staging coords: 16 threads/row, u64 granules
  const int srow = tid >> 4, scol = tid & 15, sx2 = srow & 7;

  u64 preX8 = *(const u64*)(preX + prebase);                // t=0 pre-activation
  unsigned bseq = 0;
  float zreg[4] = {0.f, 0.f, 0.f, 0.f};
  float hprev[4] = {0.f, 0.f, 0.f, 0.f};

  for (int t = 0; t < T_; ++t) {
    // =================== PHASE A: z|r = sigmoid(Wh·h + pre) ===================
    u64 v[16];
    {
      const unsigned short* src = hbs + (size_t)srow * 1024;
#pragma unroll
      for (int j = 0; j < 8; ++j) v[j]     = cload64(src + (size_t)(scol + j * 16) * 4);
#pragma unroll
      for (int j = 0; j < 8; ++j) v[8 + j] = cload64(src + 512 + (size_t)(scol + j * 16) * 4);
    }
#pragma unroll
    for (int j = 0; j < 8; ++j) {                            // commit half0
      int u = scol + j * 16;
      *(u64*)&Hs[srow * 512 + (((u >> 1) ^ sx2)) * 8 + (u & 1) * 4] = v[j];
    }
    __syncthreads();

    floatx4 acc0 = (floatx4){0.f, 0.f, 0.f, 0.f};
    floatx4 acc1 = (floatx4){0.f, 0.f, 0.f, 0.f};
#pragma unroll
    for (int ks = 0; ks < 16; ks += 2) {
      const int ck0 = ks * 4 + (lane >> 4), ck1 = ck0 + 4;
      short8 w0 = *(const short8*)&WA[arow * 1024 + ((ck0 ^ ax)) * 8];
      short8 h0 = *(const short8*)&Hs[mrow * 512 + ((ck0 ^ hx)) * 8];
      acc0 = __builtin_amdgcn_mfma_f32_16x16x32_bf16(w0, h0, acc0, 0, 0, 0);
      short8 w1 = *(const short8*)&WA[arow * 1024 + ((ck1 ^ ax)) * 8];
      short8 h1 = *(const short8*)&Hs[mrow * 512 + ((ck1 ^ hx)) * 8];
      acc1 = __builtin_amdgcn_mfma_f32_16x16x32_bf16(w1, h1, acc1, 0, 0, 0);
    }
    __syncthreads();
#pragma unroll
    for (int j = 0; j < 8; ++j) {                            // commit half1
      int u = scol + j * 16;
      *(u64*)&Hs[srow * 512 + (((u >> 1) ^ sx2)) * 8 + (u & 1) * 4] = v[8 + j];
    }
    __syncthreads();
#pragma unroll
    for (int ks = 0; ks < 16; ks += 2) {
      const int ck0 = ks * 4 + (lane >> 4), ck1 = ck0 + 4;
      short8 w0 = *(const short8*)&WA[arow * 1024 + (((64 + ck0) ^ ax)) * 8];
      short8 h0 = *(const short8*)&Hs[mrow * 512 + ((ck0 ^ hx)) * 8];
      acc0 = __builtin_amdgcn_mfma_f32_16x16x32_bf16(w0, h0, acc0, 0, 0, 0);
      short8 w1 = *(const short8*)&WA[arow * 1024 + (((64 + ck1) ^ ax)) * 8];
      short8 h1 = *(const short8*)&Hs[mrow * 512 + ((ck1 ^ hx)) * 8];
      acc1 = __builtin_amdgcn_mfma_f32_16x16x32_bf16(w1, h1, acc1, 0, 0, 0);
    }

    // epilogue A: C mapping row=(lane>>4)*4+reg -> n (W first operand), col=lane&15 -> m
    {
      floatx4 accA = acc0 + acc1;
      if (wave < 2) {
#pragma unroll
        for (int r2 = 0; r2 < 4; ++r2)
          zreg[r2] = sigmoidf_(accA[r2] + h2f((ushort)(preX8 >> (16 * r2))));
      } else {
        const floatx4 hp = *(const floatx4*)&hstash[mrow * 32 + nloc];
        u64 o = 0;
#pragma unroll
        for (int r2 = 0; r2 < 4; ++r2) {
          float rg2 = sigmoidf_(accA[r2] + h2f((ushort)(preX8 >> (16 * r2))));
          o |= (u64)f2bf(rg2 * hp[r2]) << (16 * r2);
        }
        cstore64(rh + (size_t)(r0 + mrow) * 1024 + c0 + nloc, o);
      }
    }
    ++bseq;
    gbar_sig(flags, rg, slot, bseq);
    floatx4 preI4 = prefetch16f(out + ((size_t)t << 17) + prebase);  // parked pre_i
    gbar_wait(flags, rg, bseq);

    // =================== PHASE B: i = tanh(Wi·(r*h) + pre_i); h update ===================
    {
      const unsigned short* src = rhs + (size_t)srow * 1024;
#pragma unroll
      for (int j = 0; j < 8; ++j) v[j]     = cload64(src + (size_t)(scol + j * 16) * 4);
#pragma unroll
      for (int j = 0; j < 8; ++j) v[8 + j] = cload64(src + 512 + (size_t)(scol + j * 16) * 4);
    }
#pragma unroll
    for (int j = 0; j < 8; ++j) {
      int u = scol + j * 16;
      *(u64*)&Hs[srow * 512 + (((u >> 1) ^ sx2)) * 8 + (u & 1) * 4] = v[j];
    }
    __syncthreads();

    floatx4 accB0 = (floatx4){0.f, 0.f, 0.f, 0.f};
    floatx4 accB1 = (floatx4){0.f, 0.f, 0.f, 0.f};
    const unsigned short* wb = wip + (size_t)(((wave & 1) << 4) + mrow) * 1024 + ((size_t)(wave >> 1) << 9);
    if ((wave >> 1) == 0) {
#pragma unroll
      for (int ks = 0; ks < 16; ks += 2) {
        const int ck0 = ks * 4 + (lane >> 4), ck1 = ck0 + 4;
        short8 w0 = *(const short8*)(wb + ck0 * 8);
        short8 b0 = *(const short8*)&Hs[mrow * 512 + ((ck0 ^ hx)) * 8];
        accB0 = __builtin_amdgcn_mfma_f32_16x16x32_bf16(w0, b0, accB0, 0, 0, 0);
        short8 w1 = *(const short8*)(wb + ck1 * 8);
        short8 b1 = *(const short8*)&Hs[mrow * 512 + ((ck1 ^ hx)) * 8];
        accB1 = __builtin_amdgcn_mfma_f32_16x16x32_bf16(w1, b1, accB1, 0, 0, 0);
      }
    }
    __syncthreads();
#pragma unroll
    for (int j = 0; j < 8; ++j) {
      int u = scol + j * 16;
      *(u64*)&Hs[srow * 512 + (((u >> 1) ^ sx2)) * 8 + (u & 1) * 4] = v[8 + j];
    }
    __syncthreads();
    if ((wave >> 1) == 1) {
#pragma unroll
      for (int ks = 0; ks < 16; ks += 2) {
        const int ck0 = ks * 4 + (lane >> 4), ck1 = ck0 + 4;
        short8 w0 = *(const short8*)(wb + ck0 * 8);
        short8 b0 = *(const short8*)&Hs[mrow * 512 + ((ck0 ^ hx)) * 8];
        accB0 = __builtin_amdgcn_mfma_f32_16x16x32_bf16(w0, b0, accB0, 0, 0, 0);
        short8 w1 = *(const short8*)(wb + ck1 * 8);
        short8 b1 = *(const short8*)&Hs[mrow * 512 + ((ck1 ^ hx)) * 8];
        accB1 = __builtin_amdgcn_mfma_f32_16x16x32_bf16(w1, b1, accB1, 0, 0, 0);
      }
      floatx4 sB = accB0 + accB1;
      *(floatx4*)&red[((wave - 2) << 8) + (lane << 2)] = sB;
    }
    __syncthreads();
    if (wave < 2) {
      floatx4 accB = accB0 + accB1 + *(const floatx4*)&red[(wave << 8) + (lane << 2)];
      float hn[4];
      u64 ob = 0;
#pragma unroll
      for (int r2 = 0; r2 < 4; ++r2) {
        float ivl = tanhf_(accB[r2] + preI4[r2]);
        hn[r2] = (1.f - zreg[r2]) * hprev[r2] + zreg[r2] * ivl;
        hprev[r2] = hn[r2];
        ob |= (u64)f2bf(hn[r2]) << (16 * r2);
      }
      float* po = out + ((size_t)t << 17) + prebase;
      *(floatx4*)po = (floatx4){hn[0], hn[1], hn[2], hn[3]};
      cstore64(hb + (size_t)(r0 + mrow) * 1024 + c0 + nloc, ob);
      *(floatx4*)&hstash[mrow * 32 + nloc] = (floatx4){hn[0], hn[1], hn[2], hn[3]};
    }

    if (t + 1 < T_) {
      ++bseq;
      gbar_sig(flags, rg, slot, bseq);
      preX8 = prefetch8(preX + ((size_t)(t + 1) << 17) + prebase);
      gbar_wait(flags, rg, bseq);
    }
  }
}

extern "C" void kernel_launch(void* const* d_in, const int* in_sizes, int n_in,
                              void* d_out, int out_size, void* d_ws, size_t ws_size,
                              hipStream_t stream) {
  const float* x  = (const float*)d_in[0];
  const float* Wz = (const float*)d_in[1];
  const float* bz = (const float*)d_in[2];
  const float* Wr = (const float*)d_in[3];
  const float* br = (const float*)d_in[4];
  const float* Wi = (const float*)d_in[5];
  const float* bi = (const float*)d_in[6];
  float* out = (float*)d_out;
  char* wsb = (char*)d_ws;

  unsigned short* preZ = (unsigned short*)(wsb + OFF_PREZ);
  unsigned short* preR = (unsigned short*)(wsb + OFF_PRER);
  unsigned short* wh   = (unsigned short*)(wsb + OFF_WH);
  unsigned short* wx   = (unsigned short*)(wsb + OFF_WX);
  unsigned short* xb   = (unsigned short*)(wsb + OFF_XB);
  unsigned short* hb   = (unsigned short*)(wsb + OFF_HB);
  unsigned short* rh   = (unsigned short*)(wsb + OFF_RH);
  unsigned* flags      = (unsigned*)(wsb + OFF_CTR);

  hipMemsetAsync(wsb + OFF_HB, 0, (size_t)B_ * L_ * 2, stream);   // h0 = 0
  hipMemsetAsync(wsb + OFF_CTR, 0, 16384, stream);                // barrier flags

  k_conv_x<<<8192, 256, 0, stream>>>(x, xb);
  k_conv_w<<<2304, 256, 0, stream>>>(Wz, Wr, Wi, wx, wh);
  k_pre_gemm<<<dim3(256, 24), 256, 0, stream>>>(xb, wx, preZ, preR, out, bz, br, bi);
  k_gru<<<256, 256, 0, stream>>>(wh, preZ, preR, hb, rh, out, flags);
}

// Round 4
// 2196.302 us; speedup vs baseline: 1.6382x; 1.1323x over previous
//
#include <hip/hip_runtime.h>

typedef __attribute__((ext_vector_type(8))) short short8;
typedef __attribute__((ext_vector_type(4))) float floatx4;
typedef unsigned long long u64;
typedef __attribute__((ext_vector_type(2))) unsigned long long u64x2;
typedef unsigned short ushort;

#define DEV __device__ __forceinline__

constexpr int B_ = 128, T_ = 256, D_ = 512, L_ = 1024;

// ---- workspace byte offsets (layout unchanged) ----
constexpr size_t OFF_PREZ = 0;                                  // fp16 [T][B][L]
constexpr size_t OFF_PRER = OFF_PREZ + (size_t)T_ * B_ * L_ * 2;
constexpr size_t OFF_WH   = OFF_PRER + (size_t)T_ * B_ * L_ * 2; // bf16 [3][1024][1024]
constexpr size_t OFF_WX   = OFF_WH + (size_t)3 * L_ * 1024 * 2;  // bf16 [3][1024][512]
constexpr size_t OFF_XB   = OFF_WX + (size_t)3 * L_ * 512 * 2;   // bf16 [B][T][D]
constexpr size_t OFF_HB   = OFF_XB + (size_t)B_ * T_ * D_ * 2;   // bf16 [B][L] current h
constexpr size_t OFF_RH   = OFF_HB + (size_t)B_ * L_ * 2;        // bf16 [B][L] r*h
constexpr size_t OFF_Z    = OFF_RH + (size_t)B_ * L_ * 2;        // (unused)
constexpr size_t OFF_CTR  = OFF_Z + (size_t)B_ * L_ * 4;         // barrier flags (16 KB)

DEV ushort f2bf(float f) {
  unsigned u = __float_as_uint(f);
  u += 0x7fffu + ((u >> 16) & 1u);   // RNE
  return (ushort)(u >> 16);
}
DEV ushort f2h(float f) { _Float16 h = (_Float16)f; return __builtin_bit_cast(ushort, h); }
DEV float h2f(ushort u) { _Float16 h = __builtin_bit_cast(_Float16, u); return (float)h; }
DEV float sigmoidf_(float x) { return 1.0f / (1.0f + __expf(-x)); }
DEV float tanhf_(float x) {
  float a = fabsf(x);
  float e = __expf(-2.0f * a);
  float t = (1.0f - e) / (1.0f + e);
  return copysignf(t, x);
}

// ---- agent-scope (MALL-coherent) access helpers — verified primitives ----
DEV u64 cload64(const void* p) {
  return __hip_atomic_load((const u64*)p, __ATOMIC_RELAXED, __HIP_MEMORY_SCOPE_AGENT);
}
DEV void cstore64(void* p, u64 v) {
  __hip_atomic_store((u64*)p, v, __ATOMIC_RELAXED, __HIP_MEMORY_SCOPE_AGENT);
}

DEV void gld_lds16(const void* g, void* l) {
  __builtin_amdgcn_global_load_lds(
      (const __attribute__((address_space(1))) unsigned int*)g,
      (__attribute__((address_space(3))) unsigned int*)l, 16, 0, 0);
}

// early-issue prefetches (plain cached loads, pinned at issue point)
DEV u64 prefetch8(const ushort* p) {
  u64 v; asm volatile("global_load_dwordx2 %0, %1, off" : "=v"(v) : "v"(p)); return v;
}
DEV floatx4 prefetch16f(const float* p) {
  floatx4 v; asm volatile("global_load_dwordx4 %0, %1, off" : "=v"(v) : "v"(p)); return v;
}

// ---- slab-local barrier (verified R3): 32 blocks of one batch-row group ----
DEV void gbar_sig(unsigned* flags, int rg, int slot, unsigned iv) {
  asm volatile("s_waitcnt vmcnt(0)" ::: "memory");
  __syncthreads();
  if (threadIdx.x == 0)
    __hip_atomic_store(flags + (((iv & 1) << 3) + rg) * 32 + slot, iv,
                       __ATOMIC_RELAXED, __HIP_MEMORY_SCOPE_AGENT);
}
DEV void gbar_wait(const unsigned* flags, int rg, unsigned iv) {
  if (threadIdx.x < 64) {
    const unsigned* f = flags + (((iv & 1) << 3) + rg) * 32 + (threadIdx.x & 31);
    while (__ballot(__hip_atomic_load(f, __ATOMIC_RELAXED, __HIP_MEMORY_SCOPE_AGENT) != iv))
      __builtin_amdgcn_s_sleep(1);
  }
  __syncthreads();
}

// ---------------- conversion kernels (unchanged, verified) ----------------
__global__ __launch_bounds__(256) void k_conv_x(const float* __restrict__ x,
                                                unsigned short* __restrict__ xb) {
  size_t i = ((size_t)blockIdx.x * 256 + threadIdx.x) * 8;
  float4 f0 = *(const float4*)(x + i);
  float4 f1 = *(const float4*)(x + i + 4);
  short8 o;
  o[0] = (short)f2bf(f0.x); o[1] = (short)f2bf(f0.y); o[2] = (short)f2bf(f0.z); o[3] = (short)f2bf(f0.w);
  o[4] = (short)f2bf(f1.x); o[5] = (short)f2bf(f1.y); o[6] = (short)f2bf(f1.z); o[7] = (short)f2bf(f1.w);
  *(short8*)&xb[i] = o;
}

__global__ __launch_bounds__(256) void k_conv_w(const float* __restrict__ Wz,
                                                const float* __restrict__ Wr,
                                                const float* __restrict__ Wi,
                                                unsigned short* __restrict__ wx,
                                                unsigned short* __restrict__ wh) {
  int idx = blockIdx.x * 256 + threadIdx.x;
  int g = idx / 196608;
  int rem = idx - g * 196608;
  int n = rem / 192;
  int c = rem - n * 192;
  int k = c * 8;
  const float* W = (g == 0) ? Wz : ((g == 1) ? Wr : Wi);
  const float* src = W + (size_t)n * 1536 + k;
  short8 o;
#pragma unroll
  for (int u = 0; u < 8; ++u) o[u] = (short)f2bf(src[u]);
  if (k < 512)
    *(short8*)&wx[((size_t)g * 1024 + n) * 512 + k] = o;
  else
    *(short8*)&wh[((size_t)g * 1024 + n) * 1024 + (k - 512)] = o;
}

// ---------------- x-part pre-activation GEMM (unchanged, verified) ----------------
__global__ __launch_bounds__(256) void k_pre_gemm(const unsigned short* __restrict__ xb,
                                                  const unsigned short* __restrict__ wx,
                                                  unsigned short* __restrict__ preZ,
                                                  unsigned short* __restrict__ preR,
                                                  float* __restrict__ outI,
                                                  const float* __restrict__ bz,
                                                  const float* __restrict__ br,
                                                  const float* __restrict__ bi) {
  __shared__ __align__(16) unsigned short As[128 * 64];
  __shared__ __align__(16) unsigned short Bs[128 * 64];
  const int tid = threadIdx.x;
  const int wave = tid >> 6, lane = tid & 63;
  const int m0 = blockIdx.x * 128;
  const int n0g = blockIdx.y * 128;
  const int g = n0g >> 10;
  const int n0 = n0g & 1023;
  const unsigned short* wg = wx + (size_t)g * 1024 * 512;
  const int wm = (wave >> 1) * 64, wn = (wave & 1) * 64;

  floatx4 acc[4][4];
#pragma unroll
  for (int i = 0; i < 4; ++i)
#pragma unroll
    for (int j = 0; j < 4; ++j) acc[i][j] = (floatx4){0.f, 0.f, 0.f, 0.f};

  for (int ko = 0; ko < 8; ++ko) {
    const int k0 = ko * 64;
#pragma unroll
    for (int j = 0; j < 4; ++j) {
      int rowbase = (wave * 4 + j) * 8;
      int row = rowbase + (lane >> 3);
      int clog = (lane & 7) ^ (row & 7);
      gld_lds16(xb + (size_t)(m0 + row) * 512 + k0 + clog * 8, &As[rowbase * 64]);
      gld_lds16(wg + (size_t)(n0 + row) * 512 + k0 + clog * 8, &Bs[rowbase * 64]);
    }
    __syncthreads();
#pragma unroll
    for (int ks = 0; ks < 2; ++ks) {
      short8 a[4], b[4];
      int cl = ks * 4 + (lane >> 4);
#pragma unroll
      for (int i = 0; i < 4; ++i) {
        int r = wm + i * 16 + (lane & 15);
        a[i] = *(const short8*)&As[r * 64 + ((cl ^ (r & 7)) * 8)];
      }
#pragma unroll
      for (int j = 0; j < 4; ++j) {
        int r = wn + j * 16 + (lane & 15);
        b[j] = *(const short8*)&Bs[r * 64 + ((cl ^ (r & 7)) * 8)];
      }
#pragma unroll
      for (int i = 0; i < 4; ++i)
#pragma unroll
        for (int j = 0; j < 4; ++j)
          acc[i][j] = __builtin_amdgcn_mfma_f32_16x16x32_bf16(a[i], b[j], acc[i][j], 0, 0, 0);
    }
    __syncthreads();
  }

  const float* bias = (g == 0) ? bz : ((g == 1) ? br : bi);
#pragma unroll
  for (int i = 0; i < 4; ++i)
#pragma unroll
    for (int j = 0; j < 4; ++j) {
      int ncol = n0 + wn + j * 16 + (lane & 15);
      float bv = bias[ncol];
#pragma unroll
      for (int reg = 0; reg < 4; ++reg) {
        int m = m0 + wm + i * 16 + (lane >> 4) * 4 + reg;
        int bidx = m >> 8, t = m & 255;
        size_t idx = ((size_t)(t * B_ + bidx) << 10) + ncol;
        float v = acc[i][j][reg] + bv;
        if (g == 0)      preZ[idx] = f2h(v);
        else if (g == 1) preR[idx] = f2h(v);
        else             outI[idx] = v;                // pre_i parked in d_out
      }
    }
}

// =====================================================================
// Persistent recurrent kernel — placement-independent (agent-scope MALL
// exchange). 256 blocks, 1/CU. Block p: batch rows [16*(p>>5), +16),
// latent cols [32*(p&31), +32) for z, r AND i.
// R4: ALL weight fragments register-resident per wave (1 block/CU -> up
// to 512 VGPR/wave). No W reads from LDS/L2 in the steady-state loop.
// Phase B: waves 0-1 full-K (no cross-wave reduce). Full-slab staging,
// one __syncthreads per phase. Slab-local barrier (verified R3).
// =====================================================================
__global__ __launch_bounds__(256, 1) void k_gru(const unsigned short* __restrict__ wh,
                                                const unsigned short* __restrict__ preZ,
                                                const unsigned short* __restrict__ preR,
                                                unsigned short* __restrict__ hb,
                                                unsigned short* __restrict__ rh,
                                                float* __restrict__ out,
                                                unsigned* __restrict__ flags) {
  __shared__ __align__(16) unsigned short Hs[16 * 1024];  // 32 KB full-slab staging
  __shared__ __align__(16) float hstash[512];             //  2 KB h_{t-1} f32 [16 m][32 n]

  const int tid = threadIdx.x, wave = tid >> 6, lane = tid & 63;
  const int p = blockIdx.x;
  const int rg = p >> 5, slot = p & 31;
  const int r0 = rg * 16, c0 = slot * 32;

  const int mrow = lane & 15;            // batch row within slab / operand row
  const int cksub = lane >> 4;           // k sub-chunk 0..3
  const int hx = mrow & 7;               // Hs swizzle key
  const int nloc = ((wave & 1) << 4) + (cksub << 2);  // 4 consecutive local cols

  // ---- one-time register-resident weight fragments ----
  // wfA: rows of [Wz (waves 0-1) | Wr (waves 2-3)] for this block's cols.
  // wfB: rows of Wi for this block's cols (used by waves 0-1).
  const unsigned short* wAp = wh + ((wave < 2) ? (size_t)0 : (size_t)1048576)
                                 + (size_t)(c0 + ((wave & 1) << 4) + mrow) * 1024;
  const unsigned short* wBp = wh + (size_t)2097152
                                 + (size_t)(c0 + ((wave & 1) << 4) + mrow) * 1024;
  short8 wfA[32], wfB[32];
#pragma unroll
  for (int h = 0; h < 2; ++h)
#pragma unroll
    for (int s = 0; s < 8; ++s) {
      const int cb = h * 64 + s * 8 + cksub;
      wfA[h * 16 + s * 2]     = *(const short8*)&wAp[cb * 8];
      wfA[h * 16 + s * 2 + 1] = *(const short8*)&wAp[(cb + 4) * 8];
      wfB[h * 16 + s * 2]     = *(const short8*)&wBp[cb * 8];
      wfB[h * 16 + s * 2 + 1] = *(const short8*)&wBp[(cb + 4) * 8];
    }

  hstash[tid] = 0.f;
  hstash[tid + 256] = 0.f;
  __syncthreads();

  const unsigned short* preX = (wave < 2) ? preZ : preR;
  const size_t prebase = ((size_t)(r0 + mrow) << 10) + (size_t)(c0 + nloc);
  const unsigned short* hbs = hb + (size_t)r0 * 1024;
  const unsigned short* rhs = rh + (size_t)r0 * 1024;
  const int srow = tid >> 4, scol = tid & 15, sx2 = srow & 7;

  // stage a 16x1024 bf16 slab into Hs (agent loads, chunk-paired b128 commit)
  auto stage = [&](const unsigned short* base) {
    const unsigned short* src = base + (size_t)srow * 1024;
    u64 v[16];
#pragma unroll
    for (int j = 0; j < 8; ++j) {
      const int c = scol + j * 16;
      v[2 * j]     = cload64(src + c * 8);
      v[2 * j + 1] = cload64(src + c * 8 + 4);
    }
#pragma unroll
    for (int j = 0; j < 8; ++j) {
      const int c = scol + j * 16;
      u64x2 tq; tq.x = v[2 * j]; tq.y = v[2 * j + 1];
      *(short8*)&Hs[srow * 1024 + ((c ^ sx2) * 8)] = __builtin_bit_cast(short8, tq);
    }
  };

  u64 preX8 = *(const u64*)(preX + prebase);  // t=0 pre-activation
  unsigned bseq = 0;
  float zreg[4] = {0.f, 0.f, 0.f, 0.f};
  float hprev[4] = {0.f, 0.f, 0.f, 0.f};

  for (int t = 0; t < T_; ++t) {
    // =================== PHASE A: z|r = sigmoid(Wh·h + pre) ===================
    stage(hbs);
    __syncthreads();

    floatx4 acc0 = (floatx4){0.f, 0.f, 0.f, 0.f};
    floatx4 acc1 = (floatx4){0.f, 0.f, 0.f, 0.f};
#pragma unroll
    for (int h = 0; h < 2; ++h)
#pragma unroll
      for (int s = 0; s < 8; ++s) {
        const int ck0 = h * 64 + s * 8 + cksub;
        short8 h0 = *(const short8*)&Hs[mrow * 1024 + ((ck0 ^ hx) * 8)];
        acc0 = __builtin_amdgcn_mfma_f32_16x16x32_bf16(wfA[h * 16 + s * 2], h0, acc0, 0, 0, 0);
        short8 h1 = *(const short8*)&Hs[mrow * 1024 + (((ck0 + 4) ^ hx) * 8)];
        acc1 = __builtin_amdgcn_mfma_f32_16x16x32_bf16(wfA[h * 16 + s * 2 + 1], h1, acc1, 0, 0, 0);
      }

    // epilogue A: C row=(lane>>4)*4+reg -> n (W first operand), col=lane&15 -> m
    {
      floatx4 accA = acc0 + acc1;
      if (wave < 2) {
#pragma unroll
        for (int r2 = 0; r2 < 4; ++r2)
          zreg[r2] = sigmoidf_(accA[r2] + h2f((ushort)(preX8 >> (16 * r2))));
      } else {
        const floatx4 hp = *(const floatx4*)&hstash[mrow * 32 + nloc];
        u64 o = 0;
#pragma unroll
        for (int r2 = 0; r2 < 4; ++r2) {
          float rg2 = sigmoidf_(accA[r2] + h2f((ushort)(preX8 >> (16 * r2))));
          o |= (u64)f2bf(rg2 * hp[r2]) << (16 * r2);
        }
        cstore64(rh + (size_t)(r0 + mrow) * 1024 + c0 + nloc, o);
      }
    }
    ++bseq;
    gbar_sig(flags, rg, slot, bseq);
    floatx4 preI4 = prefetch16f(out + ((size_t)t << 17) + prebase);  // parked pre_i
    gbar_wait(flags, rg, bseq);

    // =================== PHASE B: i = tanh(Wi·(r*h) + pre_i); h update ===================
    stage(rhs);
    __syncthreads();

    if (wave < 2) {
      floatx4 accB0 = (floatx4){0.f, 0.f, 0.f, 0.f};
      floatx4 accB1 = (floatx4){0.f, 0.f, 0.f, 0.f};
#pragma unroll
      for (int h = 0; h < 2; ++h)
#pragma unroll
        for (int s = 0; s < 8; ++s) {
          const int ck0 = h * 64 + s * 8 + cksub;
          short8 b0 = *(const short8*)&Hs[mrow * 1024 + ((ck0 ^ hx) * 8)];
          accB0 = __builtin_amdgcn_mfma_f32_16x16x32_bf16(wfB[h * 16 + s * 2], b0, accB0, 0, 0, 0);
          short8 b1 = *(const short8*)&Hs[mrow * 1024 + (((ck0 + 4) ^ hx) * 8)];
          accB1 = __builtin_amdgcn_mfma_f32_16x16x32_bf16(wfB[h * 16 + s * 2 + 1], b1, accB1, 0, 0, 0);
        }
      floatx4 accB = accB0 + accB1;
      float hn[4];
      u64 ob = 0;
#pragma unroll
      for (int r2 = 0; r2 < 4; ++r2) {
        float ivl = tanhf_(accB[r2] + preI4[r2]);
        hn[r2] = (1.f - zreg[r2]) * hprev[r2] + zreg[r2] * ivl;
        hprev[r2] = hn[r2];
        ob |= (u64)f2bf(hn[r2]) << (16 * r2);
      }
      float* po = out + ((size_t)t << 17) + prebase;
      *(floatx4*)po = (floatx4){hn[0], hn[1], hn[2], hn[3]};
      cstore64(hb + (size_t)(r0 + mrow) * 1024 + c0 + nloc, ob);
      *(floatx4*)&hstash[mrow * 32 + nloc] = (floatx4){hn[0], hn[1], hn[2], hn[3]};
    }

    if (t + 1 < T_) {
      ++bseq;
      gbar_sig(flags, rg, slot, bseq);
      preX8 = prefetch8(preX + ((size_t)(t + 1) << 17) + prebase);
      gbar_wait(flags, rg, bseq);
    }
  }
}

extern "C" void kernel_launch(void* const* d_in, const int* in_sizes, int n_in,
                              void* d_out, int out_size, void* d_ws, size_t ws_size,
                              hipStream_t stream) {
  const float* x  = (const float*)d_in[0];
  const float* Wz = (const float*)d_in[1];
  const float* bz = (const float*)d_in[2];
  const float* Wr = (const float*)d_in[3];
  const float* br = (const float*)d_in[4];
  const float* Wi = (const float*)d_in[5];
  const float* bi = (const float*)d_in[6];
  float* out = (float*)d_out;
  char* wsb = (char*)d_ws;

  unsigned short* preZ = (unsigned short*)(wsb + OFF_PREZ);
  unsigned short* preR = (unsigned short*)(wsb + OFF_PRER);
  unsigned short* wh   = (unsigned short*)(wsb + OFF_WH);
  unsigned short* wx   = (unsigned short*)(wsb + OFF_WX);
  unsigned short* xb   = (unsigned short*)(wsb + OFF_XB);
  unsigned short* hb   = (unsigned short*)(wsb + OFF_HB);
  unsigned short* rh   = (unsigned short*)(wsb + OFF_RH);
  unsigned* flags      = (unsigned*)(wsb + OFF_CTR);

  hipMemsetAsync(wsb + OFF_HB, 0, (size_t)B_ * L_ * 2, stream);   // h0 = 0
  hipMemsetAsync(wsb + OFF_CTR, 0, 16384, stream);                // barrier flags

  k_conv_x<<<8192, 256, 0, stream>>>(x, xb);
  k_conv_w<<<2304, 256, 0, stream>>>(Wz, Wr, Wi, wx, wh);
  k_pre_gemm<<<dim3(256, 24), 256, 0, stream>>>(xb, wx, preZ, preR, out, bz, br, bi);
  k_gru<<<256, 256, 0, stream>>>(wh, preZ, preR, hb, rh, out, flags);
}